// Round 20
// baseline (281.960 us; speedup 1.0000x reference)
//
#include <hip/hip_runtime.h>
#include <hip/hip_bf16.h>

typedef __attribute__((ext_vector_type(4))) float f32x4;
typedef __attribute__((ext_vector_type(8))) short short8;
typedef unsigned short u16;
typedef unsigned long long u64;

#define NSLICE 32
#define LDSN 12544   // >= ceil(N/8); N=100000 -> chunk=12500

static __device__ __forceinline__ u16 f2bf(float f) {
    __hip_bfloat16 h = __float2bfloat16(f);
    return __builtin_bit_cast(u16, h);
}
static __device__ __forceinline__ float bf2f(u16 u) {
    unsigned int w = ((unsigned int)u) << 16;
    return __builtin_bit_cast(float, w);
}

// ------- fused: x->bf16 convert (blocks < cvtBlocks) || slice-histogram deg count.
__global__ void k_pre(const float* __restrict__ x, u16* __restrict__ xb, int total8,
                      const int* __restrict__ dst, int* __restrict__ part,
                      int E, int chunk, int n, int cvtBlocks, int sl4) {
    __shared__ int lh[LDSN];
    int tid = threadIdx.x;
    if ((int)blockIdx.x < cvtBlocks) {
        const float4* x4 = (const float4*)x;
        int stride = cvtBlocks * 256;
        for (int i = blockIdx.x * 256 + tid; i < total8; i += stride) {
            float4 a = x4[i * 2], b = x4[i * 2 + 1];
            union { u16 u[8]; short8 v; } o;
            o.u[0] = f2bf(a.x); o.u[1] = f2bf(a.y); o.u[2] = f2bf(a.z); o.u[3] = f2bf(a.w);
            o.u[4] = f2bf(b.x); o.u[5] = f2bf(b.y); o.u[6] = f2bf(b.z); o.u[7] = f2bf(b.w);
            *(short8*)(xb + (size_t)i * 8) = o.v;
        }
    } else {
        int b = blockIdx.x - cvtBlocks;
        int g = b & 7;               // XCD pin (cvtBlocks % 8 == 0)
        int s = b >> 3;              // stream slice
        int lo = g * chunk;
        int hi = min(lo + chunk, n);
        int cnt = hi - lo;
        for (int i = tid; i < cnt; i += 256) lh[i] = 0;
        __syncthreads();
        int E4 = E >> 2;
        const int4* d4 = (const int4*)dst;
        int i40 = s * sl4, i41 = min(i40 + sl4, E4);
        for (int i = i40 + tid; i < i41; i += 256) {
            int4 v = d4[i];
            if (v.x >= lo && v.x < hi) atomicAdd(&lh[v.x - lo], 1);
            if (v.y >= lo && v.y < hi) atomicAdd(&lh[v.y - lo], 1);
            if (v.z >= lo && v.z < hi) atomicAdd(&lh[v.z - lo], 1);
            if (v.w >= lo && v.w < hi) atomicAdd(&lh[v.w - lo], 1);
        }
        if (s == NSLICE - 1) {       // tail edges (E % 4)
            for (int e = E4 * 4 + tid; e < E; e += 256) {
                int d = dst[e];
                if (d >= lo && d < hi) atomicAdd(&lh[d - lo], 1);
            }
        }
        __syncthreads();
        int* pp = part + (size_t)s * n + lo;
        for (int i = tid; i < cnt; i += 256) pp[i] = lh[i];
    }
}

// ---- scan_a: per node, prefix over the slice counts (rewrites part to bases)
__global__ void k_scan_a(int* __restrict__ part, int* __restrict__ deg,
                         int* __restrict__ bsum, int n) {
    __shared__ int sm[256];
    int tid = threadIdx.x;
    int i = blockIdx.x * 256 + tid;
    int tot = 0;
    if (i < n) {
        int run = 0;
#pragma unroll
        for (int s = 0; s < NSLICE; ++s) {
            size_t idx = (size_t)s * n + i;
            int t = part[idx];
            part[idx] = run;
            run += t;
        }
        tot = run;
        deg[i] = run;
    }
    sm[tid] = tot;
    __syncthreads();
    for (int ofs = 128; ofs > 0; ofs >>= 1) {
        if (tid < ofs) sm[tid] += sm[tid + ofs];
        __syncthreads();
    }
    if (tid == 0) bsum[blockIdx.x] = sm[0];
}

__global__ void k_scan_b(const int* __restrict__ bsum, int* __restrict__ boff, int nb,
                         int* __restrict__ offN) {
    __shared__ int s[512];
    int tid = threadIdx.x;
    int v = (tid < nb) ? bsum[tid] : 0;
    s[tid] = v;
    __syncthreads();
    for (int ofs = 1; ofs < 512; ofs <<= 1) {
        int t = (tid >= ofs) ? s[tid - ofs] : 0;
        __syncthreads();
        s[tid] += t;
        __syncthreads();
    }
    if (tid < nb) boff[tid] = s[tid] - v;          // exclusive
    if (tid == nb - 1) offN[0] = s[tid];           // total = E
}

__global__ void k_scan_c(const int* __restrict__ deg, const int* __restrict__ boff,
                         int* __restrict__ off, int n) {
    __shared__ int s[256];
    int tid = threadIdx.x;
    int i = blockIdx.x * 256 + tid;
    int v = (i < n) ? deg[i] : 0;
    s[tid] = v;
    __syncthreads();
    for (int ofs = 1; ofs < 256; ofs <<= 1) {
        int t = (tid >= ofs) ? s[tid - ofs] : 0;
        __syncthreads();
        s[tid] += t;
        __syncthreads();
    }
    int excl = s[tid] - v + boff[blockIdx.x];
    if (i < n) off[i] = excl;
}

// ---- CSR fill: block (g,s) re-scans slice s; LDS atomics only.
__global__ void k_fill(const int* __restrict__ src, const int* __restrict__ dst,
                       const int* __restrict__ off, const int* __restrict__ pre,
                       int* __restrict__ csr, int E, int chunk, int n, int sl4) {
    __shared__ int lcnt[LDSN];
    int tid = threadIdx.x;
    int g = blockIdx.x & 7;          // XCD pin
    int s = blockIdx.x >> 3;
    int lo = g * chunk;
    int hi = min(lo + chunk, n);
    int cnt = hi - lo;
    for (int i = tid; i < cnt; i += 256) lcnt[i] = 0;
    __syncthreads();
    int E4 = E >> 2;
    const int4* d4 = (const int4*)dst;
    const int4* s4 = (const int4*)src;
    const int* prs = pre + (size_t)s * n;
    int i40 = s * sl4, i41 = min(i40 + sl4, E4);
    for (int i = i40 + tid; i < i41; i += 256) {
        int4 v = d4[i];
        int4 u = s4[i];
        if (v.x >= lo && v.x < hi) {
            int p = off[v.x] + prs[v.x] + atomicAdd(&lcnt[v.x - lo], 1);
            csr[p] = u.x;
        }
        if (v.y >= lo && v.y < hi) {
            int p = off[v.y] + prs[v.y] + atomicAdd(&lcnt[v.y - lo], 1);
            csr[p] = u.y;
        }
        if (v.z >= lo && v.z < hi) {
            int p = off[v.z] + prs[v.z] + atomicAdd(&lcnt[v.z - lo], 1);
            csr[p] = u.z;
        }
        if (v.w >= lo && v.w < hi) {
            int p = off[v.w] + prs[v.w] + atomicAdd(&lcnt[v.w - lo], 1);
            csr[p] = u.w;
        }
    }
    if (s == NSLICE - 1) {           // tail edges
        for (int e = E4 * 4 + tid; e < E; e += 256) {
            int d = dst[e];
            if (d >= lo && d < hi) {
                int p = off[d] + prs[d] + atomicAdd(&lcnt[d - lo], 1);
                csr[p] = src[e];
            }
        }
    }
}

// ------ pull-aggregate: one wave per node, 4 edge slots x 16 lanes, 16 rows in flight
__global__ void k_aggr(const u16* __restrict__ xb, const int* __restrict__ off,
                       const int* __restrict__ csr, u16* __restrict__ aggr, int n) {
    int node = (blockIdx.x * blockDim.x + threadIdx.x) >> 6;
    if (node >= n) return;
    int lane = threadIdx.x & 63;
    int c = lane & 15;    // 16B slot (8 bf16), 16 slots = 256B row
    int j = lane >> 4;    // edge slot 0..3
    const short8* x8 = (const short8*)xb;
    int s0 = off[node], s1 = off[node + 1];
    float acc[8] = {0.f, 0.f, 0.f, 0.f, 0.f, 0.f, 0.f, 0.f};
    int e = s0;
    for (; e + 16 <= s1; e += 16) {   // 4 rows per slot in flight (16 rows/wave)
        int r0 = csr[e + j], r1 = csr[e + j + 4], r2 = csr[e + j + 8], r3 = csr[e + j + 12];
        short8 v0 = x8[(size_t)r0 * 16 + c];
        short8 v1 = x8[(size_t)r1 * 16 + c];
        short8 v2 = x8[(size_t)r2 * 16 + c];
        short8 v3 = x8[(size_t)r3 * 16 + c];
#pragma unroll
        for (int i = 0; i < 8; ++i)
            acc[i] += (bf2f((u16)v0[i]) + bf2f((u16)v1[i])) +
                      (bf2f((u16)v2[i]) + bf2f((u16)v3[i]));
    }
    for (int r = e + j; r < s1; r += 4) {   // tail, per-slot strided
        short8 v = x8[(size_t)csr[r] * 16 + c];
#pragma unroll
        for (int i = 0; i < 8; ++i) acc[i] += bf2f((u16)v[i]);
    }
#pragma unroll
    for (int i = 0; i < 8; ++i) {
        acc[i] += __shfl_xor(acc[i], 16, 64);
        acc[i] += __shfl_xor(acc[i], 32, 64);
    }
    if (j == 0) {
        short8 sv = x8[(size_t)node * 16 + c];   // self loop
        float inv = 1.0f / (float)(s1 - s0 + 1);
        short8 o;
#pragma unroll
        for (int i = 0; i < 8; ++i)
            o[i] = (short)f2bf((acc[i] + bf2f((u16)sv[i])) * inv);
        *(short8*)(aggr + (size_t)node * 128 + c * 8) = o;
    }
}

// ------- pass1: linear(+bias), barrier-free; bf16 x-half from xb table.
__global__ __launch_bounds__(512, 2) void k_linear(
    const u16* __restrict__ xb, const u16* __restrict__ aggr,
    const float* __restrict__ W, const float* __restrict__ b_lin,
    u16* __restrict__ hfrag,
    float* __restrict__ ssp, float* __restrict__ bnsum, float* __restrict__ bnsq,
    int n, int ntiles, int npad) {
    __shared__ u16 WT[32768];   // 64 KiB
    int tid = threadIdx.x;

    // stage W (256x128 f32 [k][col]) -> WT bf16 [col][k], XOR-swizzle (col&15)<<3
    {
        int col = tid & 127;
        int kq0 = tid >> 7;
        int mask = (col & 15) << 3;
        char* base = (char*)WT + col * 512;
#pragma unroll
        for (int i = 0; i < 16; ++i) {
            int kq = kq0 + i * 4;
            int k = kq * 4;
            float w0 = W[(size_t)(k + 0) * 128 + col];
            float w1 = W[(size_t)(k + 1) * 128 + col];
            float w2 = W[(size_t)(k + 2) * 128 + col];
            float w3 = W[(size_t)(k + 3) * 128 + col];
            u64 q = (u64)f2bf(w0) | ((u64)f2bf(w1) << 16) |
                    ((u64)f2bf(w2) << 32) | ((u64)f2bf(w3) << 48);
            *(u64*)(base + ((8 * kq) ^ mask)) = q;
        }
    }
    __syncthreads();

    int wave = tid >> 6, l = tid & 63, lr = l & 15, lg = l >> 4;
    int pair = wave >> 1, hf = wave & 1;

    // ---- read this wave's B-fragments into registers (one time) ----
    short8 breg[4][8];
#pragma unroll
    for (int ct2 = 0; ct2 < 4; ++ct2) {
        int col = hf * 64 + ct2 * 16 + lr;
        const char* rowp = (const char*)WT + col * 512;
        int mask = (col & 15) << 3;
#pragma unroll
        for (int kk = 0; kk < 8; ++kk) {
            int kb = kk * 64 + 8 * lg;
            u64 lo = *(const u64*)(rowp + (kb ^ mask));
            u64 hi = *(const u64*)(rowp + ((kb + 32) ^ mask));
            union { u64 q[2]; short8 v; } bu;
            bu.q[0] = lo; bu.q[1] = hi;
            breg[ct2][kk] = bu.v;
        }
    }

    int stride4 = gridDim.x * 4;

    // ================= phase 1: barrier-free GEMM =================
    for (int base = blockIdx.x * 4; base < ntiles; base += stride4) {
        int tile = base + pair;
        bool active = tile < ntiles;
        int rowA = tile * 16 + lr;
        bool rv = active && rowA < n;

        ushort4 xba[4], xbb[4], ua[4], ub[4];
#pragma unroll
        for (int kk = 0; kk < 4; ++kk) {
            const u16* xp = xb + (size_t)rowA * 128 + kk * 32 + 4 * lg;
            xba[kk] = rv ? *(const ushort4*)xp : make_ushort4(0, 0, 0, 0);
            xbb[kk] = rv ? *(const ushort4*)(xp + 16) : make_ushort4(0, 0, 0, 0);
        }
#pragma unroll
        for (int kk = 0; kk < 4; ++kk) {
            const u16* ap = aggr + (size_t)rowA * 128 + kk * 32 + 4 * lg;
            ua[kk] = rv ? *(const ushort4*)ap : make_ushort4(0, 0, 0, 0);
            ub[kk] = rv ? *(const ushort4*)(ap + 16) : make_ushort4(0, 0, 0, 0);
        }

        short8 av[8];
#pragma unroll
        for (int kk = 0; kk < 4; ++kk) {
            av[kk][0] = (short)xba[kk].x; av[kk][1] = (short)xba[kk].y;
            av[kk][2] = (short)xba[kk].z; av[kk][3] = (short)xba[kk].w;
            av[kk][4] = (short)xbb[kk].x; av[kk][5] = (short)xbb[kk].y;
            av[kk][6] = (short)xbb[kk].z; av[kk][7] = (short)xbb[kk].w;
            av[kk + 4][0] = (short)ua[kk].x; av[kk + 4][1] = (short)ua[kk].y;
            av[kk + 4][2] = (short)ua[kk].z; av[kk + 4][3] = (short)ua[kk].w;
            av[kk + 4][4] = (short)ub[kk].x; av[kk + 4][5] = (short)ub[kk].y;
            av[kk + 4][6] = (short)ub[kk].z; av[kk + 4][7] = (short)ub[kk].w;
        }

        f32x4 acc[4];
#pragma unroll
        for (int ct2 = 0; ct2 < 4; ++ct2) acc[ct2] = (f32x4){0.f, 0.f, 0.f, 0.f};
#pragma unroll
        for (int kk = 0; kk < 8; ++kk)
#pragma unroll
            for (int ct2 = 0; ct2 < 4; ++ct2)
                acc[ct2] = __builtin_amdgcn_mfma_f32_16x16x32_bf16(av[kk], breg[ct2][kk],
                                                                   acc[ct2], 0, 0, 0);

        float ss[4] = {0.f, 0.f, 0.f, 0.f};
#pragma unroll
        for (int ct2 = 0; ct2 < 4; ++ct2) {
            float bl = b_lin[hf * 64 + ct2 * 16 + lr];
#pragma unroll
            for (int q = 0; q < 4; ++q) {
                acc[ct2][q] += bl;
                ss[q] += acc[ct2][q] * acc[ct2][q];
            }
        }
#pragma unroll
        for (int m = 1; m < 16; m <<= 1) {
#pragma unroll
            for (int q = 0; q < 4; ++q) ss[q] += __shfl_xor(ss[q], m, 64);
        }
        if (active) {
            int rq0 = tile * 16 + 4 * lg;
            if (lr == 0)
                *(float4*)&ssp[hf * npad + rq0] = make_float4(ss[0], ss[1], ss[2], ss[3]);
            u16* hp = hfrag + (size_t)tile * 2048;
#pragma unroll
            for (int ct2 = 0; ct2 < 4; ++ct2) {
                ushort4 o;
                o.x = f2bf(acc[ct2][0]); o.y = f2bf(acc[ct2][1]);
                o.z = f2bf(acc[ct2][2]); o.w = f2bf(acc[ct2][3]);
                *(ushort4*)(hp + (hf * 4 + ct2) * 256 + l * 4) = o;
            }
        }
    }

    __syncthreads();   // partner's ssp/hfrag stores visible (same block, same L2)

    // ================= phase 2: BN partials on own tiles (L2-hot) =================
    float s1a[4] = {0, 0, 0, 0};
    float s2a[4] = {0, 0, 0, 0};
    for (int base = blockIdx.x * 4; base < ntiles; base += stride4) {
        int tile = base + pair;
        if (tile >= ntiles) continue;
        int rq0 = tile * 16 + 4 * lg;
        float rn[4];
#pragma unroll
        for (int q = 0; q < 4; ++q) {
            float s2 = ssp[rq0 + q] + ssp[npad + rq0 + q];
            rn[q] = 1.0f / fmaxf(sqrtf(s2), 1e-12f);
        }
        const u16* hp = hfrag + (size_t)tile * 2048;
#pragma unroll
        for (int ct2 = 0; ct2 < 4; ++ct2) {
            ushort4 hv = *(const ushort4*)(hp + (hf * 4 + ct2) * 256 + l * 4);
            float p1 = 0.f, p2 = 0.f;
            float h0 = bf2f(hv.x) * rn[0], h1 = bf2f(hv.y) * rn[1];
            float h2 = bf2f(hv.z) * rn[2], h3 = bf2f(hv.w) * rn[3];
            if (rq0 + 0 < n) { p1 += h0; p2 += h0 * h0; }
            if (rq0 + 1 < n) { p1 += h1; p2 += h1 * h1; }
            if (rq0 + 2 < n) { p1 += h2; p2 += h2 * h2; }
            if (rq0 + 3 < n) { p1 += h3; p2 += h3 * h3; }
            s1a[ct2] += p1; s2a[ct2] += p2;
        }
    }

    // flush BN partials
#pragma unroll
    for (int ct2 = 0; ct2 < 4; ++ct2) {
        float v1 = s1a[ct2], v2 = s2a[ct2];
        v1 += __shfl_xor(v1, 16, 64); v1 += __shfl_xor(v1, 32, 64);
        v2 += __shfl_xor(v2, 16, 64); v2 += __shfl_xor(v2, 32, 64);
        if (lg == 0) {
            atomicAdd(&bnsum[hf * 64 + ct2 * 16 + lr], v1);
            atomicAdd(&bnsq[hf * 64 + ct2 * 16 + lr], v2);
        }
    }
}

// ------- pass2: rnorm+BN apply from hfrag (ws) -> LDS -> residual+relu store
__global__ __launch_bounds__(512) void k_final(
    const u16* __restrict__ hfrag,
    const float* __restrict__ ssp, const float* __restrict__ x,
    const float* __restrict__ bnsum, const float* __restrict__ bnsq,
    const float* __restrict__ gamma, const float* __restrict__ beta,
    float* __restrict__ out, float invN, int n, int npad) {
    __shared__ float cf[256];
    __shared__ float ot[16 * 132];
    int tid = threadIdx.x;
    int tile = blockIdx.x;
    if (tid < 128) {
        float mu = bnsum[tid] * invN;
        float var = bnsq[tid] * invN - mu * mu;
        float a = gamma[tid] * rsqrtf(var + 1e-5f);
        cf[tid] = a;
        cf[128 + tid] = beta[tid] - mu * a;
    }
    __syncthreads();

    {
        const u16* hp = hfrag + (size_t)tile * 2048;
        int ct = tid >> 6, l = tid & 63;
        ushort4 hv = *(const ushort4*)(hp + ct * 256 + l * 4);
        int col = ct * 16 + (l & 15);
        float a = cf[col], b = cf[128 + col];
        int rl0 = 4 * (l >> 4);
        int rq0 = tile * 16 + rl0;
        float rn0 = 1.0f / fmaxf(sqrtf(ssp[rq0 + 0] + ssp[npad + rq0 + 0]), 1e-12f);
        float rn1 = 1.0f / fmaxf(sqrtf(ssp[rq0 + 1] + ssp[npad + rq0 + 1]), 1e-12f);
        float rn2 = 1.0f / fmaxf(sqrtf(ssp[rq0 + 2] + ssp[npad + rq0 + 2]), 1e-12f);
        float rn3 = 1.0f / fmaxf(sqrtf(ssp[rq0 + 3] + ssp[npad + rq0 + 3]), 1e-12f);
        ot[(rl0 + 0) * 132 + col] = bf2f(hv.x) * rn0 * a + b;
        ot[(rl0 + 1) * 132 + col] = bf2f(hv.y) * rn1 * a + b;
        ot[(rl0 + 2) * 132 + col] = bf2f(hv.z) * rn2 * a + b;
        ot[(rl0 + 3) * 132 + col] = bf2f(hv.w) * rn3 * a + b;
    }
    __syncthreads();

    {
        int rl = tid >> 5, c4 = tid & 31;
        int row = tile * 16 + rl;
        if (row < n) {
            float4 xv = *(const float4*)(x + (size_t)row * 128 + c4 * 4);
            const float* op = &ot[rl * 132 + c4 * 4];
            float4 o;
            o.x = fmaxf(op[0] + xv.x, 0.f);
            o.y = fmaxf(op[1] + xv.y, 0.f);
            o.z = fmaxf(op[2] + xv.z, 0.f);
            o.w = fmaxf(op[3] + xv.w, 0.f);
            *(float4*)(out + (size_t)row * 128 + c4 * 4) = o;
        }
    }
}

extern "C" void kernel_launch(void* const* d_in, const int* in_sizes, int n_in,
                              void* d_out, int out_size, void* d_ws, size_t ws_size,
                              hipStream_t stream) {
    const float* x     = (const float*)d_in[0];
    const int*   ei    = (const int*)d_in[1];
    const float* W     = (const float*)d_in[3];
    const float* b_lin = (const float*)d_in[4];
    const float* gamma = (const float*)d_in[5];
    const float* beta  = (const float*)d_in[6];
    int N = in_sizes[0] / 128;
    int E = in_sizes[1] / 2;
    const int* src = ei;
    const int* dst = ei + E;

    int ntiles = (N + 15) / 16;
    int npad = ntiles * 16;

    char* p = (char*)d_ws;
    auto alloc = [&](size_t bytes) { char* r = p; p += (bytes + 255) & ~(size_t)255; return r; };
    int*   deg   = (int*)alloc((size_t)N * 4);
    float* bnsum = (float*)alloc(128 * 4);
    float* bnsq  = (float*)alloc(128 * 4);
    size_t zoff  = (char*)bnsum - (char*)d_ws;
    int*   off   = (int*)alloc((size_t)(N + 1) * 4);
    int*   csr   = (int*)alloc((size_t)E * 4);
    int*   bsum  = (int*)alloc(512 * 4);
    int*   boff  = (int*)alloc(512 * 4);
    float* ssp   = (float*)alloc((size_t)npad * 2 * 4);
    u16*   aggr  = (u16*)alloc((size_t)N * 128 * 2);
    u16*   hfrag = (u16*)alloc((size_t)npad * 128 * 2);

    // part[NSLICE][N] aliases aggr (dead until k_aggr, which runs after k_fill);
    // NSLICE*N*4 = 12.8MB <= 25.6MB region.
    int* part = (int*)aggr;

    // bf16 x-table lives in d_out's first half (alive through k_linear)
    u16* xbf = (u16*)d_out;

    hipMemsetAsync((char*)d_ws + zoff, 0, 256 * 4, stream);   // bnsum+bnsq

    int chunk = (N + 7) / 8;          // <= LDSN
    int E4 = E >> 2;
    int sl4 = (E4 + NSLICE - 1) / NSLICE;
    const int CVTB = 768;             // multiple of 8 -> preserves &7 XCD pinning

    k_pre<<<CVTB + 8 * NSLICE, 256, 0, stream>>>(x, xbf, N * 16, dst, part,
                                                 E, chunk, N, CVTB, sl4);
    int nb = (N + 255) / 256;
    k_scan_a<<<nb, 256, 0, stream>>>(part, deg, bsum, N);
    k_scan_b<<<1, 512, 0, stream>>>(bsum, boff, nb, off + N);
    k_scan_c<<<nb, 256, 0, stream>>>(deg, boff, off, N);
    k_fill<<<8 * NSLICE, 256, 0, stream>>>(src, dst, off, part, csr, E, chunk, N, sl4);
    k_aggr<<<(int)(((size_t)N * 64 + 255) / 256), 256, 0, stream>>>(xbf, off, csr, aggr, N);
    k_linear<<<256, 512, 0, stream>>>(xbf, aggr, W, b_lin, hfrag, ssp,
                                      bnsum, bnsq, N, ntiles, npad);
    k_final<<<ntiles, 512, 0, stream>>>(hfrag, ssp, x, bnsum, bnsq, gamma, beta,
                                        (float*)d_out, 1.0f / (float)N, N, npad);
}

// Round 21
// 249.897 us; speedup vs baseline: 1.1283x; 1.1283x over previous
//
#include <hip/hip_runtime.h>
#include <hip/hip_bf16.h>

typedef __attribute__((ext_vector_type(4))) float f32x4;
typedef __attribute__((ext_vector_type(8))) short short8;
typedef unsigned short u16;
typedef unsigned long long u64;

#define NSLICE 64
#define LDSN 12544   // >= ceil(N/8); N=100000 -> chunk=12500

static __device__ __forceinline__ u16 f2bf(float f) {
    __hip_bfloat16 h = __float2bfloat16(f);
    return __builtin_bit_cast(u16, h);
}
static __device__ __forceinline__ float bf2f(u16 u) {
    unsigned int w = ((unsigned int)u) << 16;
    return __builtin_bit_cast(float, w);
}

// ------- fused: x->bf16 convert (blocks < cvtBlocks) || slice-histogram deg count.
__global__ void k_pre(const float* __restrict__ x, u16* __restrict__ xb, int total8,
                      const int* __restrict__ dst, int* __restrict__ part,
                      int E, int chunk, int n, int cvtBlocks, int sl4) {
    __shared__ int lh[LDSN];
    int tid = threadIdx.x;
    if ((int)blockIdx.x < cvtBlocks) {
        const float4* x4 = (const float4*)x;
        int stride = cvtBlocks * 256;
        for (int i = blockIdx.x * 256 + tid; i < total8; i += stride) {
            float4 a = x4[i * 2], b = x4[i * 2 + 1];
            union { u16 u[8]; short8 v; } o;
            o.u[0] = f2bf(a.x); o.u[1] = f2bf(a.y); o.u[2] = f2bf(a.z); o.u[3] = f2bf(a.w);
            o.u[4] = f2bf(b.x); o.u[5] = f2bf(b.y); o.u[6] = f2bf(b.z); o.u[7] = f2bf(b.w);
            *(short8*)(xb + (size_t)i * 8) = o.v;
        }
    } else {
        int b = blockIdx.x - cvtBlocks;
        int g = b & 7;               // XCD pin (cvtBlocks % 8 == 0)
        int s = b >> 3;              // stream slice
        int lo = g * chunk;
        int hi = min(lo + chunk, n);
        int cnt = hi - lo;
        for (int i = tid; i < cnt; i += 256) lh[i] = 0;
        __syncthreads();
        int E4 = E >> 2;
        const int4* d4 = (const int4*)dst;
        int i40 = s * sl4, i41 = min(i40 + sl4, E4);
        for (int i = i40 + tid; i < i41; i += 256) {
            int4 v = d4[i];
            if (v.x >= lo && v.x < hi) atomicAdd(&lh[v.x - lo], 1);
            if (v.y >= lo && v.y < hi) atomicAdd(&lh[v.y - lo], 1);
            if (v.z >= lo && v.z < hi) atomicAdd(&lh[v.z - lo], 1);
            if (v.w >= lo && v.w < hi) atomicAdd(&lh[v.w - lo], 1);
        }
        if (s == NSLICE - 1) {       // tail edges (E % 4)
            for (int e = E4 * 4 + tid; e < E; e += 256) {
                int d = dst[e];
                if (d >= lo && d < hi) atomicAdd(&lh[d - lo], 1);
            }
        }
        __syncthreads();
        int* pp = part + (size_t)s * n + lo;
        for (int i = tid; i < cnt; i += 256) pp[i] = lh[i];
    }
}

// ---- scan_a: per node, prefix over the 64 slice counts (rewrites part to bases)
__global__ void k_scan_a(int* __restrict__ part, int* __restrict__ deg,
                         int* __restrict__ bsum, int n) {
    __shared__ int sm[256];
    int tid = threadIdx.x;
    int i = blockIdx.x * 256 + tid;
    int tot = 0;
    if (i < n) {
        int run = 0;
#pragma unroll
        for (int s = 0; s < NSLICE; ++s) {
            size_t idx = (size_t)s * n + i;
            int t = part[idx];
            part[idx] = run;
            run += t;
        }
        tot = run;
        deg[i] = run;
    }
    sm[tid] = tot;
    __syncthreads();
    for (int ofs = 128; ofs > 0; ofs >>= 1) {
        if (tid < ofs) sm[tid] += sm[tid + ofs];
        __syncthreads();
    }
    if (tid == 0) bsum[blockIdx.x] = sm[0];
}

__global__ void k_scan_b(const int* __restrict__ bsum, int* __restrict__ boff, int nb,
                         int* __restrict__ offN) {
    __shared__ int s[512];
    int tid = threadIdx.x;
    int v = (tid < nb) ? bsum[tid] : 0;
    s[tid] = v;
    __syncthreads();
    for (int ofs = 1; ofs < 512; ofs <<= 1) {
        int t = (tid >= ofs) ? s[tid - ofs] : 0;
        __syncthreads();
        s[tid] += t;
        __syncthreads();
    }
    if (tid < nb) boff[tid] = s[tid] - v;          // exclusive
    if (tid == nb - 1) offN[0] = s[tid];           // total = E
}

__global__ void k_scan_c(const int* __restrict__ deg, const int* __restrict__ boff,
                         int* __restrict__ off, int n) {
    __shared__ int s[256];
    int tid = threadIdx.x;
    int i = blockIdx.x * 256 + tid;
    int v = (i < n) ? deg[i] : 0;
    s[tid] = v;
    __syncthreads();
    for (int ofs = 1; ofs < 256; ofs <<= 1) {
        int t = (tid >= ofs) ? s[tid - ofs] : 0;
        __syncthreads();
        s[tid] += t;
        __syncthreads();
    }
    int excl = s[tid] - v + boff[blockIdx.x];
    if (i < n) off[i] = excl;
}

// ---- CSR fill: block (g,s) re-scans slice s; LDS atomics only.
__global__ void k_fill(const int* __restrict__ src, const int* __restrict__ dst,
                       const int* __restrict__ off, const int* __restrict__ pre,
                       int* __restrict__ csr, int E, int chunk, int n, int sl4) {
    __shared__ int lcnt[LDSN];
    int tid = threadIdx.x;
    int g = blockIdx.x & 7;          // XCD pin
    int s = blockIdx.x >> 3;
    int lo = g * chunk;
    int hi = min(lo + chunk, n);
    int cnt = hi - lo;
    for (int i = tid; i < cnt; i += 256) lcnt[i] = 0;
    __syncthreads();
    int E4 = E >> 2;
    const int4* d4 = (const int4*)dst;
    const int4* s4 = (const int4*)src;
    const int* prs = pre + (size_t)s * n;
    int i40 = s * sl4, i41 = min(i40 + sl4, E4);
    for (int i = i40 + tid; i < i41; i += 256) {
        int4 v = d4[i];
        int4 u = s4[i];
        if (v.x >= lo && v.x < hi) {
            int p = off[v.x] + prs[v.x] + atomicAdd(&lcnt[v.x - lo], 1);
            csr[p] = u.x;
        }
        if (v.y >= lo && v.y < hi) {
            int p = off[v.y] + prs[v.y] + atomicAdd(&lcnt[v.y - lo], 1);
            csr[p] = u.y;
        }
        if (v.z >= lo && v.z < hi) {
            int p = off[v.z] + prs[v.z] + atomicAdd(&lcnt[v.z - lo], 1);
            csr[p] = u.z;
        }
        if (v.w >= lo && v.w < hi) {
            int p = off[v.w] + prs[v.w] + atomicAdd(&lcnt[v.w - lo], 1);
            csr[p] = u.w;
        }
    }
    if (s == NSLICE - 1) {           // tail edges
        for (int e = E4 * 4 + tid; e < E; e += 256) {
            int d = dst[e];
            if (d >= lo && d < hi) {
                int p = off[d] + prs[d] + atomicAdd(&lcnt[d - lo], 1);
                csr[p] = src[e];
            }
        }
    }
}

// ------ pull-aggregate: one wave per node, 4 edge slots x 16 lanes, 16 rows in flight
__global__ void k_aggr(const u16* __restrict__ xb, const int* __restrict__ off,
                       const int* __restrict__ csr, u16* __restrict__ aggr, int n) {
    int node = (blockIdx.x * blockDim.x + threadIdx.x) >> 6;
    if (node >= n) return;
    int lane = threadIdx.x & 63;
    int c = lane & 15;    // 16B slot (8 bf16), 16 slots = 256B row
    int j = lane >> 4;    // edge slot 0..3
    const short8* x8 = (const short8*)xb;
    int s0 = off[node], s1 = off[node + 1];
    float acc[8] = {0.f, 0.f, 0.f, 0.f, 0.f, 0.f, 0.f, 0.f};
    int e = s0;
    for (; e + 16 <= s1; e += 16) {   // 4 rows per slot in flight (16 rows/wave)
        int r0 = csr[e + j], r1 = csr[e + j + 4], r2 = csr[e + j + 8], r3 = csr[e + j + 12];
        short8 v0 = x8[(size_t)r0 * 16 + c];
        short8 v1 = x8[(size_t)r1 * 16 + c];
        short8 v2 = x8[(size_t)r2 * 16 + c];
        short8 v3 = x8[(size_t)r3 * 16 + c];
#pragma unroll
        for (int i = 0; i < 8; ++i)
            acc[i] += (bf2f((u16)v0[i]) + bf2f((u16)v1[i])) +
                      (bf2f((u16)v2[i]) + bf2f((u16)v3[i]));
    }
    for (int r = e + j; r < s1; r += 4) {   // tail, per-slot strided
        short8 v = x8[(size_t)csr[r] * 16 + c];
#pragma unroll
        for (int i = 0; i < 8; ++i) acc[i] += bf2f((u16)v[i]);
    }
#pragma unroll
    for (int i = 0; i < 8; ++i) {
        acc[i] += __shfl_xor(acc[i], 16, 64);
        acc[i] += __shfl_xor(acc[i], 32, 64);
    }
    if (j == 0) {
        short8 sv = x8[(size_t)node * 16 + c];   // self loop
        float inv = 1.0f / (float)(s1 - s0 + 1);
        short8 o;
#pragma unroll
        for (int i = 0; i < 8; ++i)
            o[i] = (short)f2bf((acc[i] + bf2f((u16)sv[i])) * inv);
        *(short8*)(aggr + (size_t)node * 128 + c * 8) = o;
    }
}

// ------- pass1: linear(+bias), barrier-free (r13 structure). Template: USEBF reads
// the x-half as bf16 from xb (hfrag relocated to ws, xb stays alive); else f32 x.
template<bool USEBF>
__global__ __launch_bounds__(512, 2) void k_linear(
    const float* __restrict__ x, const u16* __restrict__ xb,
    const u16* __restrict__ aggr,
    const float* __restrict__ W, const float* __restrict__ b_lin,
    u16* __restrict__ hfrag, int hstride, int hoff,
    float* __restrict__ ssp, float* __restrict__ bnsum, float* __restrict__ bnsq,
    int n, int ntiles, int npad) {
    __shared__ u16 WT[32768];   // 64 KiB
    int tid = threadIdx.x;

    // stage W (256x128 f32 [k][col]) -> WT bf16 [col][k], XOR-swizzle (col&15)<<3
    {
        int col = tid & 127;
        int kq0 = tid >> 7;
        int mask = (col & 15) << 3;
        char* base = (char*)WT + col * 512;
#pragma unroll
        for (int i = 0; i < 16; ++i) {
            int kq = kq0 + i * 4;
            int k = kq * 4;
            float w0 = W[(size_t)(k + 0) * 128 + col];
            float w1 = W[(size_t)(k + 1) * 128 + col];
            float w2 = W[(size_t)(k + 2) * 128 + col];
            float w3 = W[(size_t)(k + 3) * 128 + col];
            u64 q = (u64)f2bf(w0) | ((u64)f2bf(w1) << 16) |
                    ((u64)f2bf(w2) << 32) | ((u64)f2bf(w3) << 48);
            *(u64*)(base + ((8 * kq) ^ mask)) = q;
        }
    }
    __syncthreads();

    int wave = tid >> 6, l = tid & 63, lr = l & 15, lg = l >> 4;
    int pair = wave >> 1, hf = wave & 1;

    // ---- read this wave's B-fragments into registers (one time) ----
    short8 breg[4][8];
#pragma unroll
    for (int ct2 = 0; ct2 < 4; ++ct2) {
        int col = hf * 64 + ct2 * 16 + lr;
        const char* rowp = (const char*)WT + col * 512;
        int mask = (col & 15) << 3;
#pragma unroll
        for (int kk = 0; kk < 8; ++kk) {
            int kb = kk * 64 + 8 * lg;
            u64 lo = *(const u64*)(rowp + (kb ^ mask));
            u64 hi = *(const u64*)(rowp + ((kb + 32) ^ mask));
            union { u64 q[2]; short8 v; } bu;
            bu.q[0] = lo; bu.q[1] = hi;
            breg[ct2][kk] = bu.v;
        }
    }

    int stride4 = gridDim.x * 4;

    // ================= phase 1: barrier-free GEMM =================
    for (int base = blockIdx.x * 4; base < ntiles; base += stride4) {
        int tile = base + pair;
        bool active = tile < ntiles;
        int rowA = tile * 16 + lr;
        bool rv = active && rowA < n;

        ushort4 ua[4], ub[4];
        ushort4 xba[4], xbb[4];
        float4 xa[4], xc[4];
        if constexpr (USEBF) {
#pragma unroll
            for (int kk = 0; kk < 4; ++kk) {
                const u16* xp = xb + (size_t)rowA * 128 + kk * 32 + 4 * lg;
                xba[kk] = rv ? *(const ushort4*)xp : make_ushort4(0, 0, 0, 0);
                xbb[kk] = rv ? *(const ushort4*)(xp + 16) : make_ushort4(0, 0, 0, 0);
            }
        } else {
#pragma unroll
            for (int kk = 0; kk < 4; ++kk) {
                int k1 = kk * 32 + 4 * lg;
                xa[kk] = rv ? *(const float4*)(x + (size_t)rowA * 128 + k1)
                            : make_float4(0.f, 0.f, 0.f, 0.f);
                xc[kk] = rv ? *(const float4*)(x + (size_t)rowA * 128 + k1 + 16)
                            : make_float4(0.f, 0.f, 0.f, 0.f);
            }
        }
#pragma unroll
        for (int kk = 0; kk < 4; ++kk) {
            const u16* ap = aggr + (size_t)rowA * 128 + kk * 32 + 4 * lg;
            ua[kk] = rv ? *(const ushort4*)ap : make_ushort4(0, 0, 0, 0);
            ub[kk] = rv ? *(const ushort4*)(ap + 16) : make_ushort4(0, 0, 0, 0);
        }

        short8 av[8];
#pragma unroll
        for (int kk = 0; kk < 4; ++kk) {
            if constexpr (USEBF) {
                av[kk][0] = (short)xba[kk].x; av[kk][1] = (short)xba[kk].y;
                av[kk][2] = (short)xba[kk].z; av[kk][3] = (short)xba[kk].w;
                av[kk][4] = (short)xbb[kk].x; av[kk][5] = (short)xbb[kk].y;
                av[kk][6] = (short)xbb[kk].z; av[kk][7] = (short)xbb[kk].w;
            } else {
                av[kk][0] = (short)f2bf(xa[kk].x); av[kk][1] = (short)f2bf(xa[kk].y);
                av[kk][2] = (short)f2bf(xa[kk].z); av[kk][3] = (short)f2bf(xa[kk].w);
                av[kk][4] = (short)f2bf(xc[kk].x); av[kk][5] = (short)f2bf(xc[kk].y);
                av[kk][6] = (short)f2bf(xc[kk].z); av[kk][7] = (short)f2bf(xc[kk].w);
            }
            av[kk + 4][0] = (short)ua[kk].x; av[kk + 4][1] = (short)ua[kk].y;
            av[kk + 4][2] = (short)ua[kk].z; av[kk + 4][3] = (short)ua[kk].w;
            av[kk + 4][4] = (short)ub[kk].x; av[kk + 4][5] = (short)ub[kk].y;
            av[kk + 4][6] = (short)ub[kk].z; av[kk + 4][7] = (short)ub[kk].w;
        }

        f32x4 acc[4];
#pragma unroll
        for (int ct2 = 0; ct2 < 4; ++ct2) acc[ct2] = (f32x4){0.f, 0.f, 0.f, 0.f};
#pragma unroll
        for (int kk = 0; kk < 8; ++kk)
#pragma unroll
            for (int ct2 = 0; ct2 < 4; ++ct2)
                acc[ct2] = __builtin_amdgcn_mfma_f32_16x16x32_bf16(av[kk], breg[ct2][kk],
                                                                   acc[ct2], 0, 0, 0);

        float ss[4] = {0.f, 0.f, 0.f, 0.f};
#pragma unroll
        for (int ct2 = 0; ct2 < 4; ++ct2) {
            float bl = b_lin[hf * 64 + ct2 * 16 + lr];
#pragma unroll
            for (int q = 0; q < 4; ++q) {
                acc[ct2][q] += bl;
                ss[q] += acc[ct2][q] * acc[ct2][q];
            }
        }
#pragma unroll
        for (int m = 1; m < 16; m <<= 1) {
#pragma unroll
            for (int q = 0; q < 4; ++q) ss[q] += __shfl_xor(ss[q], m, 64);
        }
        if (active) {
            int rq0 = tile * 16 + 4 * lg;
            if (lr == 0)
                *(float4*)&ssp[hf * npad + rq0] = make_float4(ss[0], ss[1], ss[2], ss[3]);
            u16* hp = hfrag + (size_t)tile * hstride + hoff;
#pragma unroll
            for (int ct2 = 0; ct2 < 4; ++ct2) {
                ushort4 o;
                o.x = f2bf(acc[ct2][0]); o.y = f2bf(acc[ct2][1]);
                o.z = f2bf(acc[ct2][2]); o.w = f2bf(acc[ct2][3]);
                *(ushort4*)(hp + (hf * 4 + ct2) * 256 + l * 4) = o;
            }
        }
    }

    __syncthreads();   // partner's ssp/hfrag stores visible (same block, same L2)

    // ================= phase 2: BN partials on own tiles (L2-hot) =================
    float s1a[4] = {0, 0, 0, 0};
    float s2a[4] = {0, 0, 0, 0};
    for (int base = blockIdx.x * 4; base < ntiles; base += stride4) {
        int tile = base + pair;
        if (tile >= ntiles) continue;
        int rq0 = tile * 16 + 4 * lg;
        float rn[4];
#pragma unroll
        for (int q = 0; q < 4; ++q) {
            float s2 = ssp[rq0 + q] + ssp[npad + rq0 + q];
            rn[q] = 1.0f / fmaxf(sqrtf(s2), 1e-12f);
        }
        const u16* hp = hfrag + (size_t)tile * hstride + hoff;
#pragma unroll
        for (int ct2 = 0; ct2 < 4; ++ct2) {
            ushort4 hv = *(const ushort4*)(hp + (hf * 4 + ct2) * 256 + l * 4);
            float p1 = 0.f, p2 = 0.f;
            float h0 = bf2f(hv.x) * rn[0], h1 = bf2f(hv.y) * rn[1];
            float h2 = bf2f(hv.z) * rn[2], h3 = bf2f(hv.w) * rn[3];
            if (rq0 + 0 < n) { p1 += h0; p2 += h0 * h0; }
            if (rq0 + 1 < n) { p1 += h1; p2 += h1 * h1; }
            if (rq0 + 2 < n) { p1 += h2; p2 += h2 * h2; }
            if (rq0 + 3 < n) { p1 += h3; p2 += h3 * h3; }
            s1a[ct2] += p1; s2a[ct2] += p2;
        }
    }

    // flush BN partials
#pragma unroll
    for (int ct2 = 0; ct2 < 4; ++ct2) {
        float v1 = s1a[ct2], v2 = s2a[ct2];
        v1 += __shfl_xor(v1, 16, 64); v1 += __shfl_xor(v1, 32, 64);
        v2 += __shfl_xor(v2, 16, 64); v2 += __shfl_xor(v2, 32, 64);
        if (lg == 0) {
            atomicAdd(&bnsum[hf * 64 + ct2 * 16 + lr], v1);
            atomicAdd(&bnsq[hf * 64 + ct2 * 16 + lr], v2);
        }
    }
}

// ------- pass2: rnorm+BN apply; hfrag location parameterized
__global__ __launch_bounds__(512) void k_final(
    const u16* __restrict__ hfrag, int hstride, int hoff,
    const float* __restrict__ ssp, const float* __restrict__ x,
    const float* __restrict__ bnsum, const float* __restrict__ bnsq,
    const float* __restrict__ gamma, const float* __restrict__ beta,
    float* __restrict__ out, float invN, int n, int npad) {
    __shared__ float cf[256];
    __shared__ float ot[16 * 132];
    int tid = threadIdx.x;
    int tile = blockIdx.x;
    if (tid < 128) {
        float mu = bnsum[tid] * invN;
        float var = bnsq[tid] * invN - mu * mu;
        float a = gamma[tid] * rsqrtf(var + 1e-5f);
        cf[tid] = a;
        cf[128 + tid] = beta[tid] - mu * a;
    }
    __syncthreads();

    {
        const u16* hp = hfrag + (size_t)tile * hstride + hoff;
        int ct = tid >> 6, l = tid & 63;
        ushort4 hv = *(const ushort4*)(hp + ct * 256 + l * 4);
        int col = ct * 16 + (l & 15);
        float a = cf[col], b = cf[128 + col];
        int rl0 = 4 * (l >> 4);
        int rq0 = tile * 16 + rl0;
        float rn0 = 1.0f / fmaxf(sqrtf(ssp[rq0 + 0] + ssp[npad + rq0 + 0]), 1e-12f);
        float rn1 = 1.0f / fmaxf(sqrtf(ssp[rq0 + 1] + ssp[npad + rq0 + 1]), 1e-12f);
        float rn2 = 1.0f / fmaxf(sqrtf(ssp[rq0 + 2] + ssp[npad + rq0 + 2]), 1e-12f);
        float rn3 = 1.0f / fmaxf(sqrtf(ssp[rq0 + 3] + ssp[npad + rq0 + 3]), 1e-12f);
        ot[(rl0 + 0) * 132 + col] = bf2f(hv.x) * rn0 * a + b;
        ot[(rl0 + 1) * 132 + col] = bf2f(hv.y) * rn1 * a + b;
        ot[(rl0 + 2) * 132 + col] = bf2f(hv.z) * rn2 * a + b;
        ot[(rl0 + 3) * 132 + col] = bf2f(hv.w) * rn3 * a + b;
    }
    __syncthreads();   // all hfrag reads done before any overwrite below

    {
        int rl = tid >> 5, c4 = tid & 31;
        int row = tile * 16 + rl;
        if (row < n) {
            float4 xv = *(const float4*)(x + (size_t)row * 128 + c4 * 4);
            const float* op = &ot[rl * 132 + c4 * 4];
            float4 o;
            o.x = fmaxf(op[0] + xv.x, 0.f);
            o.y = fmaxf(op[1] + xv.y, 0.f);
            o.z = fmaxf(op[2] + xv.z, 0.f);
            o.w = fmaxf(op[3] + xv.w, 0.f);
            *(float4*)(out + (size_t)row * 128 + c4 * 4) = o;
        }
    }
}

extern "C" void kernel_launch(void* const* d_in, const int* in_sizes, int n_in,
                              void* d_out, int out_size, void* d_ws, size_t ws_size,
                              hipStream_t stream) {
    const float* x     = (const float*)d_in[0];
    const int*   ei    = (const int*)d_in[1];
    const float* W     = (const float*)d_in[3];
    const float* b_lin = (const float*)d_in[4];
    const float* gamma = (const float*)d_in[5];
    const float* beta  = (const float*)d_in[6];
    int N = in_sizes[0] / 128;
    int E = in_sizes[1] / 2;
    const int* src = ei;
    const int* dst = ei + E;

    int ntiles = (N + 15) / 16;
    int npad = ntiles * 16;

    char* p = (char*)d_ws;
    auto alloc = [&](size_t bytes) { char* r = p; p += (bytes + 255) & ~(size_t)255; return r; };
    int*   deg   = (int*)alloc((size_t)N * 4);
    float* bnsum = (float*)alloc(128 * 4);
    float* bnsq  = (float*)alloc(128 * 4);
    size_t zoff  = (char*)bnsum - (char*)d_ws;
    int*   off   = (int*)alloc((size_t)(N + 1) * 4);
    int*   csr   = (int*)alloc((size_t)E * 4);
    int*   bsum  = (int*)alloc(512 * 4);
    int*   boff  = (int*)alloc(512 * 4);
    float* ssp   = (float*)alloc((size_t)npad * 2 * 4);
    u16*   aggr  = (u16*)alloc((size_t)N * 128 * 2);

    // part[NSLICE][N] aliases aggr (dead until k_aggr, which runs after k_fill)
    int* part = (int*)aggr;   // NSLICE*N*4 = N*128*2 bytes exactly

    // bf16 x-table lives in d_out's first half
    u16* xbf = (u16*)d_out;

    // hfrag: prefer workspace (keeps xbf alive -> bf16 x-half in k_linear);
    // fallback: tile-local upper half of d_out (r13 scheme, f32 x-half).
    size_t hbytes = (size_t)N * 128 * 2;
    size_t used = (size_t)(p - (char*)d_ws);
    bool useBf = (used + hbytes + 256) <= ws_size;
    u16* hfrag; int hstride, hoff;
    if (useBf) {
        hfrag = (u16*)alloc(hbytes);
        hstride = 2048; hoff = 0;
    } else {
        hfrag = (u16*)d_out;
        hstride = 4096; hoff = 2048;
    }

    hipMemsetAsync((char*)d_ws + zoff, 0, 256 * 4, stream);   // bnsum+bnsq

    int chunk = (N + 7) / 8;          // <= LDSN
    int E4 = E >> 2;
    int sl4 = (E4 + NSLICE - 1) / NSLICE;
    const int CVTB = 768;             // multiple of 8 -> preserves &7 XCD pinning

    k_pre<<<CVTB + 8 * NSLICE, 256, 0, stream>>>(x, xbf, N * 16, dst, part,
                                                 E, chunk, N, CVTB, sl4);
    int nb = (N + 255) / 256;
    k_scan_a<<<nb, 256, 0, stream>>>(part, deg, bsum, N);
    k_scan_b<<<1, 512, 0, stream>>>(bsum, boff, nb, off + N);
    k_scan_c<<<nb, 256, 0, stream>>>(deg, boff, off, N);
    k_fill<<<8 * NSLICE, 256, 0, stream>>>(src, dst, off, part, csr, E, chunk, N, sl4);
    k_aggr<<<(int)(((size_t)N * 64 + 255) / 256), 256, 0, stream>>>(xbf, off, csr, aggr, N);
    if (useBf) {
        k_linear<true><<<256, 512, 0, stream>>>(x, xbf, aggr, W, b_lin,
                                                hfrag, hstride, hoff,
                                                ssp, bnsum, bnsq, N, ntiles, npad);
    } else {
        k_linear<false><<<256, 512, 0, stream>>>(x, xbf, aggr, W, b_lin,
                                                 hfrag, hstride, hoff,
                                                 ssp, bnsum, bnsq, N, ntiles, npad);
    }
    k_final<<<ntiles, 512, 0, stream>>>(hfrag, hstride, hoff, ssp, x,
                                        bnsum, bnsq, gamma, beta,
                                        (float*)d_out, 1.0f / (float)N, N, npad);
}